// Round 2
// baseline (9228.284 us; speedup 1.0000x reference)
//
#include <hip/hip_runtime.h>
#include <hip/hip_bf16.h>

// Problem constants
#define NTOK   32768          // 32 * 1024 tokens
#define BATCH  32
#define SEQ    1024
#define DIMD   768
#define HEADS  12
#define HDIM   64
#define MFEAT  384
#define HIDDEN 3072
#define SCALE  0.35355339059327379f   // 64^-0.25
#define HALF_SCALE2 0.0625f           // 0.5 * SCALE^2
#define RSM    0.05103103630798288f   // 1/sqrt(384)

static __device__ __forceinline__ float bf2f(unsigned short u) {
    return __uint_as_float(((unsigned)u) << 16);
}
static __device__ __forceinline__ unsigned short f2bf(float f) {
    unsigned u = __float_as_uint(f);
    return (unsigned short)((u + 0x7FFFu + ((u >> 16) & 1u)) >> 16);  // RNE
}
static __device__ __forceinline__ float gelu_tanh(float v) {
    const float c = 0.7978845608028654f;
    float u = c * (v + 0.044715f * v * v * v);
    return 0.5f * v * (1.0f + tanhf(u));
}

// ---------------- per-row LN stats: (mu, rsig) for rows of [NTOK, 768] -----
__global__ __launch_bounds__(256) void rowstats_kernel(
    const float* __restrict__ x, float2* __restrict__ st) {
    const size_t row = blockIdx.x;
    const float* xr = x + row * DIMD;
    const int t = threadIdx.x;
    const float v0 = xr[t], v1 = xr[t + 256], v2 = xr[t + 512];
    float s  = v0 + v1 + v2;
    float sq = v0 * v0 + v1 * v1 + v2 * v2;
    const int lane = t & 63, w = t >> 6;
    #pragma unroll
    for (int off = 32; off > 0; off >>= 1) {
        s  += __shfl_down(s, off, 64);
        sq += __shfl_down(sq, off, 64);
    }
    __shared__ float red[2][4];
    if (lane == 0) { red[0][w] = s; red[1][w] = sq; }
    __syncthreads();
    if (t == 0) {
        s  = red[0][0] + red[0][1] + red[0][2] + red[0][3];
        sq = red[1][0] + red[1][1] + red[1][2] + red[1][3];
        const float mu  = s * (1.0f / DIMD);
        const float var = sq * (1.0f / DIMD) - mu * mu;
        st[row] = make_float2(mu, rsqrtf(var + 1e-5f));
    }
}

// ---------------- fp32 GEMM, fused A-sources and epilogues -----------------
// C = op(A)[T,K] @ W[K,Nc] + bias (+resid)(+gelu)
// ASRC: 0 = plain f32, 1 = f32 with fused LayerNorm, 2 = bf16
// 128x128 tile, BK=16, 256 threads, 8x8 microtile.
template <int ASRC, int ACT, bool RES, bool OBF16>
__global__ __launch_bounds__(256) void gemm_t(
    const void* __restrict__ Araw, const float2* __restrict__ stats,
    const float* __restrict__ lng, const float* __restrict__ lnb,
    const float* __restrict__ W, const float* __restrict__ bias,
    const float* __restrict__ resid, void* __restrict__ Craw,
    int K, int Nc) {
    __shared__ float As[16][128];
    __shared__ float Bs[16][128];
    const int col0 = blockIdx.x << 7;
    const int row0 = blockIdx.y << 7;
    const int t = threadIdx.x;
    const int tx8 = (t & 15) << 3;
    const int ty8 = (t >> 4) << 3;
    const int ar0 = t >> 2, ak = (t & 3) << 2;
    const int bk0 = t >> 5, bc = (t & 31) << 2;

    const float* Af = (const float*)Araw;
    const unsigned short* Ab = (const unsigned short*)Araw;
    const size_t arowA = (size_t)(row0 + ar0) * K + ak;
    const size_t arowB = (size_t)(row0 + ar0 + 64) * K + ak;
    const float* Bp0 = W + (size_t)bk0 * Nc + col0 + bc;
    const float* Bp1 = W + (size_t)(bk0 + 8) * Nc + col0 + bc;

    float2 st0 = make_float2(0.f, 0.f), st1 = st0;
    if constexpr (ASRC == 1) {
        st0 = stats[row0 + ar0];
        st1 = stats[row0 + ar0 + 64];
    }

    float acc[8][8] = {};
    float4 a0f, a1f, g4, b4;
    ushort4 a0h, a1h;
    float4 b0, b1;

    auto fetch = [&](int k0) {
        if constexpr (ASRC == 2) {
            a0h = *(const ushort4*)(Ab + arowA + k0);
            a1h = *(const ushort4*)(Ab + arowB + k0);
        } else {
            a0f = *(const float4*)(Af + arowA + k0);
            a1f = *(const float4*)(Af + arowB + k0);
            if constexpr (ASRC == 1) {
                g4 = *(const float4*)(lng + k0 + ak);
                b4 = *(const float4*)(lnb + k0 + ak);
            }
        }
        b0 = *(const float4*)(Bp0 + (size_t)k0 * Nc);
        b1 = *(const float4*)(Bp1 + (size_t)k0 * Nc);
    };
    auto stash = [&]() {
        float v0[4], v1[4];
        if constexpr (ASRC == 2) {
            v0[0] = bf2f(a0h.x); v0[1] = bf2f(a0h.y); v0[2] = bf2f(a0h.z); v0[3] = bf2f(a0h.w);
            v1[0] = bf2f(a1h.x); v1[1] = bf2f(a1h.y); v1[2] = bf2f(a1h.z); v1[3] = bf2f(a1h.w);
        } else {
            v0[0] = a0f.x; v0[1] = a0f.y; v0[2] = a0f.z; v0[3] = a0f.w;
            v1[0] = a1f.x; v1[1] = a1f.y; v1[2] = a1f.z; v1[3] = a1f.w;
            if constexpr (ASRC == 1) {
                const float gg[4] = {g4.x, g4.y, g4.z, g4.w};
                const float bb[4] = {b4.x, b4.y, b4.z, b4.w};
                #pragma unroll
                for (int j = 0; j < 4; ++j) {
                    v0[j] = (v0[j] - st0.x) * st0.y * gg[j] + bb[j];
                    v1[j] = (v1[j] - st1.x) * st1.y * gg[j] + bb[j];
                }
            }
        }
        #pragma unroll
        for (int j = 0; j < 4; ++j) { As[ak + j][ar0] = v0[j]; As[ak + j][ar0 + 64] = v1[j]; }
        *(float4*)&Bs[bk0][bc] = b0;
        *(float4*)&Bs[bk0 + 8][bc] = b1;
    };

    fetch(0);
    int k0 = 0;
    for (;;) {
        stash();
        __syncthreads();
        k0 += 16;
        const bool more = (k0 < K);
        if (more) fetch(k0);
        #pragma unroll
        for (int kk = 0; kk < 16; ++kk) {
            const float4 av0 = *(const float4*)&As[kk][ty8];
            const float4 av1 = *(const float4*)&As[kk][ty8 + 4];
            const float4 bv0 = *(const float4*)&Bs[kk][tx8];
            const float4 bv1 = *(const float4*)&Bs[kk][tx8 + 4];
            const float ar[8] = {av0.x, av0.y, av0.z, av0.w, av1.x, av1.y, av1.z, av1.w};
            const float br[8] = {bv0.x, bv0.y, bv0.z, bv0.w, bv1.x, bv1.y, bv1.z, bv1.w};
            #pragma unroll
            for (int i = 0; i < 8; ++i)
                #pragma unroll
                for (int j = 0; j < 8; ++j)
                    acc[i][j] += ar[i] * br[j];
        }
        __syncthreads();
        if (!more) break;
    }

    const float4 bvlo = *(const float4*)&bias[col0 + tx8];
    const float4 bvhi = *(const float4*)&bias[col0 + tx8 + 4];
    const float bb[8] = {bvlo.x, bvlo.y, bvlo.z, bvlo.w, bvhi.x, bvhi.y, bvhi.z, bvhi.w};
    #pragma unroll
    for (int i = 0; i < 8; ++i) {
        const size_t base = (size_t)(row0 + ty8 + i) * Nc + col0 + tx8;
        float v[8];
        #pragma unroll
        for (int j = 0; j < 8; ++j) v[j] = acc[i][j] + bb[j];
        if constexpr (RES) {
            const float4 r0 = *(const float4*)&resid[base];
            const float4 r1 = *(const float4*)&resid[base + 4];
            v[0] += r0.x; v[1] += r0.y; v[2] += r0.z; v[3] += r0.w;
            v[4] += r1.x; v[5] += r1.y; v[6] += r1.z; v[7] += r1.w;
        }
        if constexpr (ACT == 1) {
            #pragma unroll
            for (int j = 0; j < 8; ++j) v[j] = gelu_tanh(v[j]);
        }
        if constexpr (OBF16) {
            unsigned short* Cb = (unsigned short*)Craw;
            *(ushort4*)&Cb[base]     = make_ushort4(f2bf(v[0]), f2bf(v[1]), f2bf(v[2]), f2bf(v[3]));
            *(ushort4*)&Cb[base + 4] = make_ushort4(f2bf(v[4]), f2bf(v[5]), f2bf(v[6]), f2bf(v[7]));
        } else {
            float* Cf = (float*)Craw;
            *(float4*)&Cf[base]     = make_float4(v[0], v[1], v[2], v[3]);
            *(float4*)&Cf[base + 4] = make_float4(v[4], v[5], v[6], v[7]);
        }
    }
}

// ---------------- Phase A: per (b,h): phi(k), ktv = phi_k^T v, ksum --------
__global__ __launch_bounds__(256) void performer_ktv(
    const unsigned short* __restrict__ qkvb, const float* __restrict__ worf,
    float* __restrict__ ktv, float* __restrict__ ksum) {
    const int h = blockIdx.x, b = blockIdx.y;
    const int bh = b * HEADS + h;
    __shared__ float Wsm[64][MFEAT];    // 96 KB
    __shared__ float Ks[16][64];
    __shared__ float Vs[16][64];
    __shared__ float Phi[16][MFEAT];    // 24 KB
    __shared__ float Sq[16];
    const int t = threadIdx.x;
    {
        const float4* wsrc = (const float4*)(worf + (size_t)h * 64 * MFEAT);
        float4* wdst = (float4*)&Wsm[0][0];
        for (int i = t; i < 64 * MFEAT / 4; i += 256) wdst[i] = wsrc[i];
    }
    const int mt = t & 63, ct = t >> 6;
    float acc[6][16] = {};
    float ks[6] = {};
    const unsigned short* kbase = qkvb + (size_t)b * SEQ * 2304 + 768 + h * 64;
    const unsigned short* vbase = kbase + 768;
    __syncthreads();

    for (int n0 = 0; n0 < SEQ; n0 += 16) {
        {
            const int tok = t >> 4, c4 = (t & 15) << 2;
            const ushort4 ku = *(const ushort4*)(kbase + (size_t)(n0 + tok) * 2304 + c4);
            const ushort4 vu = *(const ushort4*)(vbase + (size_t)(n0 + tok) * 2304 + c4);
            Ks[tok][c4 + 0] = bf2f(ku.x); Ks[tok][c4 + 1] = bf2f(ku.y);
            Ks[tok][c4 + 2] = bf2f(ku.z); Ks[tok][c4 + 3] = bf2f(ku.w);
            Vs[tok][c4 + 0] = bf2f(vu.x); Vs[tok][c4 + 1] = bf2f(vu.y);
            Vs[tok][c4 + 2] = bf2f(vu.z); Vs[tok][c4 + 3] = bf2f(vu.w);
        }
        __syncthreads();
        if (t < 16) {
            float s = 0.f;
            #pragma unroll
            for (int c = 0; c < 64; ++c) { const float u = Ks[t][c]; s += u * u; }
            Sq[t] = HALF_SCALE2 * s;
        }
        __syncthreads();
        {   // phi: 4 tokens x 6 m per thread
            const int tg = t >> 6;
            const int mg = t & 63;
            float sm[4][6] = {};
            for (int c = 0; c < 64; ++c) {
                const float k0 = Ks[tg * 4 + 0][c], k1 = Ks[tg * 4 + 1][c];
                const float k2 = Ks[tg * 4 + 2][c], k3 = Ks[tg * 4 + 3][c];
                #pragma unroll
                for (int j = 0; j < 6; ++j) {
                    const float wv = Wsm[c][mg + 64 * j];
                    sm[0][j] += k0 * wv; sm[1][j] += k1 * wv;
                    sm[2][j] += k2 * wv; sm[3][j] += k3 * wv;
                }
            }
            #pragma unroll
            for (int q = 0; q < 4; ++q) {
                const float sq = Sq[tg * 4 + q];
                #pragma unroll
                for (int j = 0; j < 6; ++j)
                    Phi[tg * 4 + q][mg + 64 * j] = expf(SCALE * sm[q][j] - sq) * RSM;
            }
        }
        __syncthreads();
        #pragma unroll 1
        for (int i = 0; i < 16; ++i) {
            float pv[6];
            #pragma unroll
            for (int j = 0; j < 6; ++j) pv[j] = Phi[i][mt + 64 * j];
            const float4 v0 = *(const float4*)&Vs[i][ct * 16];
            const float4 v1 = *(const float4*)&Vs[i][ct * 16 + 4];
            const float4 v2 = *(const float4*)&Vs[i][ct * 16 + 8];
            const float4 v3 = *(const float4*)&Vs[i][ct * 16 + 12];
            const float vv[16] = {v0.x, v0.y, v0.z, v0.w, v1.x, v1.y, v1.z, v1.w,
                                  v2.x, v2.y, v2.z, v2.w, v3.x, v3.y, v3.z, v3.w};
            #pragma unroll
            for (int jm = 0; jm < 6; ++jm)
                #pragma unroll
                for (int jc = 0; jc < 16; ++jc)
                    acc[jm][jc] += pv[jm] * vv[jc];
            if (ct == 0) {
                #pragma unroll
                for (int j = 0; j < 6; ++j) ks[j] += pv[j];
            }
        }
        __syncthreads();
    }

    float* kdst = ktv + (size_t)bh * MFEAT * 64;
    #pragma unroll
    for (int jm = 0; jm < 6; ++jm) {
        const int m = mt + 64 * jm;
        #pragma unroll
        for (int q = 0; q < 4; ++q)
            *(float4*)&kdst[(size_t)m * 64 + ct * 16 + q * 4] =
                make_float4(acc[jm][q * 4 + 0], acc[jm][q * 4 + 1],
                            acc[jm][q * 4 + 2], acc[jm][q * 4 + 3]);
    }
    if (ct == 0) {
        #pragma unroll
        for (int j = 0; j < 6; ++j) ksum[(size_t)bh * MFEAT + mt + 64 * j] = ks[j];
    }
}

// ---------------- Phase B: per (b,h,64-token tile): out = phi(q)@ktv / D ---
__global__ __launch_bounds__(256) void performer_out(
    const unsigned short* __restrict__ qkvb, const float* __restrict__ worf,
    const float* __restrict__ ktv, const float* __restrict__ ksum,
    unsigned short* __restrict__ attn) {
    const int h = blockIdx.y, b = blockIdx.z;
    const int n0 = blockIdx.x << 6;
    const int bh = b * HEADS + h;
    __shared__ float Qs[64][64];
    __shared__ float Wc[64][96];
    __shared__ float Ktvc[96][64];
    __shared__ float Phic[64][100];
    __shared__ float Sqs[64];
    __shared__ float KsumC[96];
    const int t = threadIdx.x;
    const unsigned short* qbase = qkvb + (size_t)b * SEQ * 2304 + h * 64;
    for (int i = t; i < 1024; i += 256) {
        const int tok = i >> 4, c4 = (i & 15) << 2;
        const ushort4 qu = *(const ushort4*)(qbase + (size_t)(n0 + tok) * 2304 + c4);
        Qs[tok][c4 + 0] = bf2f(qu.x); Qs[tok][c4 + 1] = bf2f(qu.y);
        Qs[tok][c4 + 2] = bf2f(qu.z); Qs[tok][c4 + 3] = bf2f(qu.w);
    }
    __syncthreads();
    if (t < 64) {
        float s = 0.f;
        #pragma unroll
        for (int c = 0; c < 64; ++c) { const float u = Qs[t][c]; s += u * u; }
        Sqs[t] = HALF_SCALE2 * s;
    }
    const int ti = t >> 2, ci = t & 3;
    float oacc[16] = {};
    float Dacc = 0.f;
    const float* wbase = worf + (size_t)h * 64 * MFEAT;
    const float* ktvbase = ktv + (size_t)bh * MFEAT * 64;

    for (int m0 = 0; m0 < MFEAT; m0 += 96) {
        __syncthreads();
        for (int i = t; i < 1536; i += 256) {
            const int c = i / 24, m4 = (i % 24) << 2;
            *(float4*)&Wc[c][m4] = *(const float4*)(wbase + (size_t)c * MFEAT + m0 + m4);
        }
        for (int i = t; i < 1536; i += 256) {
            const int mm = i >> 4, c4 = (i & 15) << 2;
            *(float4*)&Ktvc[mm][c4] = *(const float4*)(ktvbase + (size_t)(m0 + mm) * 64 + c4);
        }
        if (t < 96) KsumC[t] = ksum[(size_t)bh * MFEAT + m0 + t];
        __syncthreads();
        {   // phi(q): 4 tokens x 6 m per thread
            const int tg = t >> 4, mj = t & 15;
            const int tok0 = tg << 2;
            float sm[4][6] = {};
            for (int c = 0; c < 64; ++c) {
                const float a0 = Qs[tok0][c], a1 = Qs[tok0 + 1][c];
                const float a2 = Qs[tok0 + 2][c], a3 = Qs[tok0 + 3][c];
                #pragma unroll
                for (int j = 0; j < 6; ++j) {
                    const float wv = Wc[c][mj + 16 * j];
                    sm[0][j] += a0 * wv; sm[1][j] += a1 * wv;
                    sm[2][j] += a2 * wv; sm[3][j] += a3 * wv;
                }
            }
            #pragma unroll
            for (int q = 0; q < 4; ++q) {
                const float sq = Sqs[tok0 + q];
                #pragma unroll
                for (int j = 0; j < 6; ++j)
                    Phic[tok0 + q][mj + 16 * j] = expf(SCALE * sm[q][j] - sq) * RSM;
            }
        }
        __syncthreads();
        #pragma unroll 1
        for (int mm = 0; mm < 96; ++mm) {
            const float p = Phic[ti][mm];
            const float* kr = &Ktvc[mm][ci << 4];
            const float4 k0 = *(const float4*)kr;
            const float4 k1 = *(const float4*)(kr + 4);
            const float4 k2 = *(const float4*)(kr + 8);
            const float4 k3 = *(const float4*)(kr + 12);
            oacc[0]  += p * k0.x; oacc[1]  += p * k0.y; oacc[2]  += p * k0.z; oacc[3]  += p * k0.w;
            oacc[4]  += p * k1.x; oacc[5]  += p * k1.y; oacc[6]  += p * k1.z; oacc[7]  += p * k1.w;
            oacc[8]  += p * k2.x; oacc[9]  += p * k2.y; oacc[10] += p * k2.z; oacc[11] += p * k2.w;
            oacc[12] += p * k3.x; oacc[13] += p * k3.y; oacc[14] += p * k3.z; oacc[15] += p * k3.w;
            Dacc += p * KsumC[mm];
        }
    }
    const float inv = 1.0f / (Dacc + 1e-8f);
    unsigned short* dst = attn + (size_t)(b * SEQ + n0 + ti) * DIMD + h * 64 + (ci << 4);
    #pragma unroll
    for (int q = 0; q < 4; ++q)
        *(ushort4*)(dst + q * 4) = make_ushort4(
            f2bf(oacc[q * 4 + 0] * inv), f2bf(oacc[q * 4 + 1] * inv),
            f2bf(oacc[q * 4 + 2] * inv), f2bf(oacc[q * 4 + 3] * inv));
}

// ---------------------------------------------------------------------------
extern "C" void kernel_launch(void* const* d_in, const int* in_sizes, int n_in,
                              void* d_out, int out_size, void* d_ws, size_t ws_size,
                              hipStream_t stream) {
    const float* x      = (const float*)d_in[0];
    const float* ln1_g  = (const float*)d_in[1];
    const float* ln1_b  = (const float*)d_in[2];
    const float* qkv_w  = (const float*)d_in[3];
    const float* qkv_b  = (const float*)d_in[4];
    const float* w_orf  = (const float*)d_in[5];
    const float* proj_w = (const float*)d_in[6];
    const float* proj_b = (const float*)d_in[7];
    const float* ln2_g  = (const float*)d_in[8];
    const float* ln2_b  = (const float*)d_in[9];
    const float* fc1_w  = (const float*)d_in[10];
    const float* fc1_b  = (const float*)d_in[11];
    const float* fc2_w  = (const float*)d_in[12];
    const float* fc2_b  = (const float*)d_in[13];
    float* out = (float*)d_out;

    // Workspace layout (bytes). Total 240,189,440 B ~= 229 MiB.
    char* wsb = (char*)d_ws;
    unsigned short* qkvb = (unsigned short*)wsb;                 // bf16 T*2304  = 150,994,944 B
    unsigned short* attn = (unsigned short*)(wsb + 150994944);   // bf16 T*768   =  50,331,648 B
    float*  ktvb   = (float*) (wsb + 201326592);                 // f32 B*H*384*64 = 37,748,736 B
    float*  ksum   = (float*) (wsb + 239075328);                 // f32 B*H*384  =     589,824 B
    float2* stats1 = (float2*)(wsb + 239665152);                 // f32 T*2      =     262,144 B
    float2* stats2 = (float2*)(wsb + 239927296);                 // f32 T*2      =     262,144 B
    unsigned short* hid = (unsigned short*)wsb;                  // bf16 T*3072, aliases qkvb+attn

    // 1) per-row LN1 stats of x
    rowstats_kernel<<<NTOK, 256, 0, stream>>>(x, stats1);
    // 2) qkv = LN1(x) @ qkv_w + qkv_b   (bf16 out)
    gemm_t<1, 0, false, true><<<dim3(2304 / 128, NTOK / 128), 256, 0, stream>>>(
        x, stats1, ln1_g, ln1_b, qkv_w, qkv_b, nullptr, qkvb, DIMD, 2304);
    // 3) phase A: ktv + ksum
    performer_ktv<<<dim3(HEADS, BATCH), 256, 0, stream>>>(qkvb, w_orf, ktvb, ksum);
    // 4) phase B: attn out (bf16)
    performer_out<<<dim3(16, HEADS, BATCH), 256, 0, stream>>>(qkvb, w_orf, ktvb, ksum, attn);
    // 5) h = x + attn @ proj_w + proj_b  -> d_out (f32)
    gemm_t<2, 0, true, false><<<dim3(DIMD / 128, NTOK / 128), 256, 0, stream>>>(
        attn, nullptr, nullptr, nullptr, proj_w, proj_b, x, out, DIMD, DIMD);
    // 6) per-row LN2 stats of h
    rowstats_kernel<<<NTOK, 256, 0, stream>>>(out, stats2);
    // 7) hid = gelu(LN2(h) @ fc1_w + fc1_b)  (bf16 out, aliases qkvb+attn)
    gemm_t<1, 1, false, true><<<dim3(HIDDEN / 128, NTOK / 128), 256, 0, stream>>>(
        out, stats2, ln2_g, ln2_b, fc1_w, fc1_b, nullptr, hid, DIMD, HIDDEN);
    // 8) out = h + hid @ fc2_w + fc2_b   (in-place residual on d_out)
    gemm_t<2, 0, true, false><<<dim3(DIMD / 128, NTOK / 128), 256, 0, stream>>>(
        hid, nullptr, nullptr, nullptr, fc2_w, fc2_b, out, out, HIDDEN, DIMD);
}

// Round 3
// 3358.258 us; speedup vs baseline: 2.7479x; 2.7479x over previous
//
#include <hip/hip_runtime.h>
#include <hip/hip_bf16.h>

// Problem constants
#define NTOK   32768          // 32 * 1024 tokens
#define BATCH  32
#define SEQ    1024
#define DIMD   768
#define HEADS  12
#define HDIM   64
#define MFEAT  384
#define HIDDEN 3072
#define SCALE  0.35355339059327379f   // 64^-0.25
#define HALF_SCALE2 0.0625f           // 0.5 * SCALE^2
#define RSM    0.05103103630798288f   // 1/sqrt(384)

typedef __attribute__((ext_vector_type(8))) short bf16x8;
typedef __attribute__((ext_vector_type(4))) float f32x4;

static __device__ __forceinline__ float bf2f(unsigned short u) {
    return __uint_as_float(((unsigned)u) << 16);
}
static __device__ __forceinline__ unsigned short f2bf(float f) {
    unsigned u = __float_as_uint(f);
    return (unsigned short)((u + 0x7FFFu + ((u >> 16) & 1u)) >> 16);  // RNE
}
static __device__ __forceinline__ float gelu_tanh(float v) {
    const float c = 0.7978845608028654f;
    float u = c * (v + 0.044715f * v * v * v);
    return 0.5f * v * (1.0f + tanhf(u));
}
static __device__ __forceinline__ void gload16(const void* g, void* l) {
    __builtin_amdgcn_global_load_lds(
        (const __attribute__((address_space(1))) void*)g,
        (__attribute__((address_space(3))) void*)l, 16, 0, 0);
}

// ---------------- fused LayerNorm -> bf16 (one block per 768-elem row) -----
__global__ __launch_bounds__(256) void ln_bf16(
    const float* __restrict__ x, const float* __restrict__ g,
    const float* __restrict__ bta, unsigned short* __restrict__ o) {
    const size_t row = blockIdx.x;
    const float* xr = x + row * DIMD;
    unsigned short* orow = o + row * DIMD;
    const int t = threadIdx.x;
    const float v0 = xr[t], v1 = xr[t + 256], v2 = xr[t + 512];
    float s  = v0 + v1 + v2;
    float sq = v0 * v0 + v1 * v1 + v2 * v2;
    const int lane = t & 63, w = t >> 6;
    #pragma unroll
    for (int off = 32; off > 0; off >>= 1) {
        s  += __shfl_down(s, off, 64);
        sq += __shfl_down(sq, off, 64);
    }
    __shared__ float red[2][4];
    if (lane == 0) { red[0][w] = s; red[1][w] = sq; }
    __syncthreads();
    s  = red[0][0] + red[0][1] + red[0][2] + red[0][3];
    sq = red[1][0] + red[1][1] + red[1][2] + red[1][3];
    const float mu  = s * (1.0f / DIMD);
    const float var = sq * (1.0f / DIMD) - mu * mu;
    const float r = rsqrtf(var + 1e-5f);
    orow[t]       = f2bf((v0 - mu) * r * g[t]       + bta[t]);
    orow[t + 256] = f2bf((v1 - mu) * r * g[t + 256] + bta[t + 256]);
    orow[t + 512] = f2bf((v2 - mu) * r * g[t + 512] + bta[t + 512]);
}

// ---------------- weight convert + transpose: W[K,N] f32 -> Wt[N,K] bf16 ---
__global__ __launch_bounds__(256) void wconv(
    const float* __restrict__ W, unsigned short* __restrict__ Wt, int K, int N) {
    __shared__ float tile[32][33];
    const int n0 = blockIdx.x << 5, k0 = blockIdx.y << 5;
    const int tn = threadIdx.x & 31, tg = threadIdx.x >> 5;   // tg 0..7
    #pragma unroll
    for (int i = 0; i < 4; ++i) {
        const int k = (tg << 2) + i;
        tile[k][tn] = W[(size_t)(k0 + k) * N + n0 + tn];
    }
    __syncthreads();
    #pragma unroll
    for (int i = 0; i < 4; ++i) {
        const int n = (tg << 2) + i;
        Wt[(size_t)(n0 + n) * K + k0 + tn] = f2bf(tile[tn][n]);
    }
}

// ---------------- bf16 MFMA GEMM: C = A[M,K] @ Wt[N,K]^T + bias ------------
// 128x128 tile, BK=32, 256 threads (4 waves), wave owns 64x64 (4x4 frags of
// 16x16x32 MFMA). Double-buffered LDS, global_load_lds width-16 staging.
// A,Wt bf16 row-major K-contiguous; bias f32; resid f32; out f32 or bf16.
template <int ACT, bool RES, bool OBF16>
__global__ __launch_bounds__(256, 2) void gemm_mfma(
    const unsigned short* __restrict__ A, const unsigned short* __restrict__ Wt,
    const float* __restrict__ bias, const float* __restrict__ resid,
    void* __restrict__ Craw, int K, int N) {
    __shared__ unsigned short As[2][128 * 32];   // 8 KB per buffer
    __shared__ unsigned short Bs[2][128 * 32];
    const int t = threadIdx.x;
    const int w = t >> 6, l = t & 63;
    const int row0 = blockIdx.y << 7, col0 = blockIdx.x << 7;
    const int wr = (w >> 1) << 6, wc = (w & 1) << 6;

    // staging source pointers: wave w covers tile rows [w*32, w*32+32)
    // lane l -> row chunk (l>>2), 16B chunk (l&3) within the 64B row
    const unsigned short* ag0 = A  + (size_t)(row0 + w * 32 + (l >> 2)) * K + ((l & 3) << 3);
    const unsigned short* ag1 = ag0 + (size_t)16 * K;
    const unsigned short* bg0 = Wt + (size_t)(col0 + w * 32 + (l >> 2)) * K + ((l & 3) << 3);
    const unsigned short* bg1 = bg0 + (size_t)16 * K;

    f32x4 acc[4][4] = {};
    const int NT = K >> 5;

    auto stage = [&](int bi, int s) {
        const size_t ko = (size_t)s << 5;   // 32 bf16 per K-step
        gload16(ag0 + ko, &As[bi][w * 1024]);
        gload16(ag1 + ko, &As[bi][w * 1024 + 512]);
        gload16(bg0 + ko, &Bs[bi][w * 1024]);
        gload16(bg1 + ko, &Bs[bi][w * 1024 + 512]);
    };

    stage(0, 0);
    const int lr = l & 15, lk = (l >> 4) << 3, lg = l >> 4;
    for (int s = 0; s < NT; ++s) {
        __syncthreads();                       // buf[s&1] staged; prior reads of buf[(s+1)&1] done
        if (s + 1 < NT) stage((s + 1) & 1, s + 1);
        const unsigned short* ab = &As[s & 1][0];
        const unsigned short* bb = &Bs[s & 1][0];
        bf16x8 af[4], bfr[4];
        #pragma unroll
        for (int f = 0; f < 4; ++f) {
            af[f]  = *(const bf16x8*)(ab + (wr + f * 16 + lr) * 32 + lk);
            bfr[f] = *(const bf16x8*)(bb + (wc + f * 16 + lr) * 32 + lk);
        }
        #pragma unroll
        for (int fi = 0; fi < 4; ++fi)
            #pragma unroll
            for (int fj = 0; fj < 4; ++fj)
                acc[fi][fj] = __builtin_amdgcn_mfma_f32_16x16x32_bf16(
                    af[fi], bfr[fj], acc[fi][fj], 0, 0, 0);
    }

    // epilogue: C row = row0+wr+fi*16+lg*4+r, col = col0+wc+fj*16+lr
    float bv[4];
    #pragma unroll
    for (int fj = 0; fj < 4; ++fj) bv[fj] = bias[col0 + wc + fj * 16 + lr];
    #pragma unroll
    for (int fi = 0; fi < 4; ++fi) {
        #pragma unroll
        for (int r = 0; r < 4; ++r) {
            const int row = row0 + wr + fi * 16 + lg * 4 + r;
            const size_t base = (size_t)row * N + col0 + wc + lr;
            #pragma unroll
            for (int fj = 0; fj < 4; ++fj) {
                float v = acc[fi][fj][r] + bv[fj];
                if constexpr (RES) v += resid[base + fj * 16];
                if constexpr (ACT == 1) v = gelu_tanh(v);
                if constexpr (OBF16) ((unsigned short*)Craw)[base + fj * 16] = f2bf(v);
                else                 ((float*)Craw)[base + fj * 16] = v;
            }
        }
    }
}

// ---------------- Phase A: per (b,h): phi(k), ktv = phi_k^T v, ksum --------
__global__ __launch_bounds__(256) void performer_ktv(
    const unsigned short* __restrict__ qkvb, const float* __restrict__ worf,
    float* __restrict__ ktv, float* __restrict__ ksum) {
    const int h = blockIdx.x, b = blockIdx.y;
    const int bh = b * HEADS + h;
    __shared__ float Wsm[64][MFEAT];    // 96 KB
    __shared__ float Ks[16][64];
    __shared__ float Vs[16][64];
    __shared__ float Phi[16][MFEAT];    // 24 KB
    __shared__ float Sq[16];
    const int t = threadIdx.x;
    {
        const float4* wsrc = (const float4*)(worf + (size_t)h * 64 * MFEAT);
        float4* wdst = (float4*)&Wsm[0][0];
        for (int i = t; i < 64 * MFEAT / 4; i += 256) wdst[i] = wsrc[i];
    }
    const int mt = t & 63, ct = t >> 6;
    float acc[6][16] = {};
    float ks[6] = {};
    const unsigned short* kbase = qkvb + (size_t)b * SEQ * 2304 + 768 + h * 64;
    const unsigned short* vbase = kbase + 768;
    __syncthreads();

    for (int n0 = 0; n0 < SEQ; n0 += 16) {
        {
            const int tok = t >> 4, c4 = (t & 15) << 2;
            const ushort4 ku = *(const ushort4*)(kbase + (size_t)(n0 + tok) * 2304 + c4);
            const ushort4 vu = *(const ushort4*)(vbase + (size_t)(n0 + tok) * 2304 + c4);
            Ks[tok][c4 + 0] = bf2f(ku.x); Ks[tok][c4 + 1] = bf2f(ku.y);
            Ks[tok][c4 + 2] = bf2f(ku.z); Ks[tok][c4 + 3] = bf2f(ku.w);
            Vs[tok][c4 + 0] = bf2f(vu.x); Vs[tok][c4 + 1] = bf2f(vu.y);
            Vs[tok][c4 + 2] = bf2f(vu.z); Vs[tok][c4 + 3] = bf2f(vu.w);
        }
        __syncthreads();
        if (t < 16) {
            float s = 0.f;
            #pragma unroll
            for (int c = 0; c < 64; ++c) { const float u = Ks[t][c]; s += u * u; }
            Sq[t] = HALF_SCALE2 * s;
        }
        __syncthreads();
        {   // phi: 4 tokens x 6 m per thread
            const int tg = t >> 6;
            const int mg = t & 63;
            float sm[4][6] = {};
            for (int c = 0; c < 64; ++c) {
                const float k0 = Ks[tg * 4 + 0][c], k1 = Ks[tg * 4 + 1][c];
                const float k2 = Ks[tg * 4 + 2][c], k3 = Ks[tg * 4 + 3][c];
                #pragma unroll
                for (int j = 0; j < 6; ++j) {
                    const float wv = Wsm[c][mg + 64 * j];
                    sm[0][j] += k0 * wv; sm[1][j] += k1 * wv;
                    sm[2][j] += k2 * wv; sm[3][j] += k3 * wv;
                }
            }
            #pragma unroll
            for (int q = 0; q < 4; ++q) {
                const float sq = Sq[tg * 4 + q];
                #pragma unroll
                for (int j = 0; j < 6; ++j)
                    Phi[tg * 4 + q][mg + 64 * j] = expf(SCALE * sm[q][j] - sq) * RSM;
            }
        }
        __syncthreads();
        #pragma unroll 1
        for (int i = 0; i < 16; ++i) {
            float pv[6];
            #pragma unroll
            for (int j = 0; j < 6; ++j) pv[j] = Phi[i][mt + 64 * j];
            const float4 v0 = *(const float4*)&Vs[i][ct * 16];
            const float4 v1 = *(const float4*)&Vs[i][ct * 16 + 4];
            const float4 v2 = *(const float4*)&Vs[i][ct * 16 + 8];
            const float4 v3 = *(const float4*)&Vs[i][ct * 16 + 12];
            const float vv[16] = {v0.x, v0.y, v0.z, v0.w, v1.x, v1.y, v1.z, v1.w,
                                  v2.x, v2.y, v2.z, v2.w, v3.x, v3.y, v3.z, v3.w};
            #pragma unroll
            for (int jm = 0; jm < 6; ++jm)
                #pragma unroll
                for (int jc = 0; jc < 16; ++jc)
                    acc[jm][jc] += pv[jm] * vv[jc];
            if (ct == 0) {
                #pragma unroll
                for (int j = 0; j < 6; ++j) ks[j] += pv[j];
            }
        }
        __syncthreads();
    }

    float* kdst = ktv + (size_t)bh * MFEAT * 64;
    #pragma unroll
    for (int jm = 0; jm < 6; ++jm) {
        const int m = mt + 64 * jm;
        #pragma unroll
        for (int q = 0; q < 4; ++q)
            *(float4*)&kdst[(size_t)m * 64 + ct * 16 + q * 4] =
                make_float4(acc[jm][q * 4 + 0], acc[jm][q * 4 + 1],
                            acc[jm][q * 4 + 2], acc[jm][q * 4 + 3]);
    }
    if (ct == 0) {
        #pragma unroll
        for (int j = 0; j < 6; ++j) ksum[(size_t)bh * MFEAT + mt + 64 * j] = ks[j];
    }
}

// ---------------- Phase B: per (b,h,64-token tile): out = phi(q)@ktv / D ---
__global__ __launch_bounds__(256) void performer_out(
    const unsigned short* __restrict__ qkvb, const float* __restrict__ worf,
    const float* __restrict__ ktv, const float* __restrict__ ksum,
    unsigned short* __restrict__ attn) {
    const int h = blockIdx.y, b = blockIdx.z;
    const int n0 = blockIdx.x << 6;
    const int bh = b * HEADS + h;
    __shared__ float Qs[64][64];
    __shared__ float Wc[64][96];
    __shared__ float Ktvc[96][64];
    __shared__ float Phic[64][100];
    __shared__ float Sqs[64];
    __shared__ float KsumC[96];
    const int t = threadIdx.x;
    const unsigned short* qbase = qkvb + (size_t)b * SEQ * 2304 + h * 64;
    for (int i = t; i < 1024; i += 256) {
        const int tok = i >> 4, c4 = (i & 15) << 2;
        const ushort4 qu = *(const ushort4*)(qbase + (size_t)(n0 + tok) * 2304 + c4);
        Qs[tok][c4 + 0] = bf2f(qu.x); Qs[tok][c4 + 1] = bf2f(qu.y);
        Qs[tok][c4 + 2] = bf2f(qu.z); Qs[tok][c4 + 3] = bf2f(qu.w);
    }
    __syncthreads();
    if (t < 64) {
        float s = 0.f;
        #pragma unroll
        for (int c = 0; c < 64; ++c) { const float u = Qs[t][c]; s += u * u; }
        Sqs[t] = HALF_SCALE2 * s;
    }
    const int ti = t >> 2, ci = t & 3;
    float oacc[16] = {};
    float Dacc = 0.f;
    const float* wbase = worf + (size_t)h * 64 * MFEAT;
    const float* ktvbase = ktv + (size_t)bh * MFEAT * 64;

    for (int m0 = 0; m0 < MFEAT; m0 += 96) {
        __syncthreads();
        for (int i = t; i < 1536; i += 256) {
            const int c = i / 24, m4 = (i % 24) << 2;
            *(float4*)&Wc[c][m4] = *(const float4*)(wbase + (size_t)c * MFEAT + m0 + m4);
        }
        for (int i = t; i < 1536; i += 256) {
            const int mm = i >> 4, c4 = (i & 15) << 2;
            *(float4*)&Ktvc[mm][c4] = *(const float4*)(ktvbase + (size_t)(m0 + mm) * 64 + c4);
        }
        if (t < 96) KsumC[t] = ksum[(size_t)bh * MFEAT + m0 + t];
        __syncthreads();
        {   // phi(q): 4 tokens x 6 m per thread
            const int tg = t >> 4, mj = t & 15;
            const int tok0 = tg << 2;
            float sm[4][6] = {};
            for (int c = 0; c < 64; ++c) {
                const float a0 = Qs[tok0][c], a1 = Qs[tok0 + 1][c];
                const float a2 = Qs[tok0 + 2][c], a3 = Qs[tok0 + 3][c];
                #pragma unroll
                for (int j = 0; j < 6; ++j) {
                    const float wv = Wc[c][mj + 16 * j];
                    sm[0][j] += a0 * wv; sm[1][j] += a1 * wv;
                    sm[2][j] += a2 * wv; sm[3][j] += a3 * wv;
                }
            }
            #pragma unroll
            for (int q = 0; q < 4; ++q) {
                const float sq = Sqs[tok0 + q];
                #pragma unroll
                for (int j = 0; j < 6; ++j)
                    Phic[tok0 + q][mj + 16 * j] = expf(SCALE * sm[q][j] - sq) * RSM;
            }
        }
        __syncthreads();
        #pragma unroll 1
        for (int mm = 0; mm < 96; ++mm) {
            const float p = Phic[ti][mm];
            const float* kr = &Ktvc[mm][ci << 4];
            const float4 k0 = *(const float4*)kr;
            const float4 k1 = *(const float4*)(kr + 4);
            const float4 k2 = *(const float4*)(kr + 8);
            const float4 k3 = *(const float4*)(kr + 12);
            oacc[0]  += p * k0.x; oacc[1]  += p * k0.y; oacc[2]  += p * k0.z; oacc[3]  += p * k0.w;
            oacc[4]  += p * k1.x; oacc[5]  += p * k1.y; oacc[6]  += p * k1.z; oacc[7]  += p * k1.w;
            oacc[8]  += p * k2.x; oacc[9]  += p * k2.y; oacc[10] += p * k2.z; oacc[11] += p * k2.w;
            oacc[12] += p * k3.x; oacc[13] += p * k3.y; oacc[14] += p * k3.z; oacc[15] += p * k3.w;
            Dacc += p * KsumC[mm];
        }
    }
    const float inv = 1.0f / (Dacc + 1e-8f);
    unsigned short* dst = attn + (size_t)(b * SEQ + n0 + ti) * DIMD + h * 64 + (ci << 4);
    #pragma unroll
    for (int q = 0; q < 4; ++q)
        *(ushort4*)(dst + q * 4) = make_ushort4(
            f2bf(oacc[q * 4 + 0] * inv), f2bf(oacc[q * 4 + 1] * inv),
            f2bf(oacc[q * 4 + 2] * inv), f2bf(oacc[q * 4 + 3] * inv));
}

// ---------------------------------------------------------------------------
extern "C" void kernel_launch(void* const* d_in, const int* in_sizes, int n_in,
                              void* d_out, int out_size, void* d_ws, size_t ws_size,
                              hipStream_t stream) {
    const float* x      = (const float*)d_in[0];
    const float* ln1_g  = (const float*)d_in[1];
    const float* ln1_b  = (const float*)d_in[2];
    const float* qkv_w  = (const float*)d_in[3];
    const float* qkv_b  = (const float*)d_in[4];
    const float* w_orf  = (const float*)d_in[5];
    const float* proj_w = (const float*)d_in[6];
    const float* proj_b = (const float*)d_in[7];
    const float* ln2_g  = (const float*)d_in[8];
    const float* ln2_b  = (const float*)d_in[9];
    const float* fc1_w  = (const float*)d_in[10];
    const float* fc1_b  = (const float*)d_in[11];
    const float* fc2_w  = (const float*)d_in[12];
    const float* fc2_b  = (const float*)d_in[13];
    float* out = (float*)d_out;

    // Workspace layout (bytes). Total 265,814,016 B = 253.5 MiB.
    char* wsb = (char*)d_ws;
    unsigned short* qkvb = (unsigned short*)wsb;                  // bf16 T*2304 [0, 150994944)
    unsigned short* attn = (unsigned short*)(wsb + 150994944);    // bf16 T*768  [.., 201326592)
    unsigned short* xln  = (unsigned short*)(wsb + 201326592);    // bf16 T*768  [.., 251658240)
    // after xln dies (post-qkv GEMM) this region is reused:
    float* ktvb = (float*)(wsb + 201326592);                      // f32 B*H*384*64 = 37,748,736 B
    float* ksum = (float*)(wsb + 239075328);                      // f32 B*H*384 -> ends 239,665,152
    unsigned short* y2 = xln;                                     // ln2 out (ktv dead by then)
    unsigned short* hid = qkvb;                                   // bf16 T*3072 aliases qkvb+attn
    unsigned short* qkv_wt = (unsigned short*)(wsb + 251658240);  // [2304,768]  3,538,944 B
    unsigned short* proj_wt = (unsigned short*)(wsb + 255197184); // [768,768]   1,179,648 B
    unsigned short* fc1_wt = (unsigned short*)(wsb + 256376832);  // [3072,768]  4,718,592 B
    unsigned short* fc2_wt = (unsigned short*)(wsb + 261095424);  // [768,3072]  4,718,592 B

    // 0) weight convert+transpose to bf16 [N,K]
    wconv<<<dim3(2304 / 32, 768 / 32), 256, 0, stream>>>(qkv_w, qkv_wt, DIMD, 2304);
    wconv<<<dim3(768 / 32, 768 / 32), 256, 0, stream>>>(proj_w, proj_wt, DIMD, DIMD);
    wconv<<<dim3(3072 / 32, 768 / 32), 256, 0, stream>>>(fc1_w, fc1_wt, DIMD, HIDDEN);
    wconv<<<dim3(768 / 32, 3072 / 32), 256, 0, stream>>>(fc2_w, fc2_wt, HIDDEN, DIMD);
    // 1) xln = LN1(x) (bf16)
    ln_bf16<<<NTOK, 256, 0, stream>>>(x, ln1_g, ln1_b, xln);
    // 2) qkv = xln @ qkv_w + qkv_b (bf16 out)
    gemm_mfma<0, false, true><<<dim3(2304 / 128, NTOK / 128), 256, 0, stream>>>(
        xln, qkv_wt, qkv_b, nullptr, qkvb, DIMD, 2304);
    // 3) phase A: ktv + ksum
    performer_ktv<<<dim3(HEADS, BATCH), 256, 0, stream>>>(qkvb, w_orf, ktvb, ksum);
    // 4) phase B: attn out (bf16)
    performer_out<<<dim3(16, HEADS, BATCH), 256, 0, stream>>>(qkvb, w_orf, ktvb, ksum, attn);
    // 5) h = x + attn @ proj_w + proj_b -> d_out (f32)
    gemm_mfma<0, true, false><<<dim3(DIMD / 128, NTOK / 128), 256, 0, stream>>>(
        attn, proj_wt, proj_b, x, out, DIMD, DIMD);
    // 6) y2 = LN2(h) (bf16)
    ln_bf16<<<NTOK, 256, 0, stream>>>(out, ln2_g, ln2_b, y2);
    // 7) hid = gelu(y2 @ fc1_w + fc1_b) (bf16)
    gemm_mfma<1, false, true><<<dim3(HIDDEN / 128, NTOK / 128), 256, 0, stream>>>(
        y2, fc1_wt, fc1_b, nullptr, hid, DIMD, HIDDEN);
    // 8) out = h + hid @ fc2_w + fc2_b (in-place residual on d_out)
    gemm_mfma<0, true, false><<<dim3(DIMD / 128, NTOK / 128), 256, 0, stream>>>(
        hid, fc2_wt, fc2_b, out, out, HIDDEN, DIMD);
}

// Round 4
// 1009.770 us; speedup vs baseline: 9.1390x; 3.3258x over previous
//
#include <hip/hip_runtime.h>
#include <hip/hip_bf16.h>

// Problem constants
#define NTOK   32768          // 32 * 1024 tokens
#define BATCH  32
#define SEQ    1024
#define DIMD   768
#define HEADS  12
#define HDIM   64
#define MFEAT  384
#define HIDDEN 3072
#define SCALE  0.35355339059327379f   // 64^-0.25
#define HALF_SCALE2 0.0625f           // 0.5 * SCALE^2
#define EPSP   3.84e-6f               // 1e-8 / RSM^2 (RSM factors cancel in out)

typedef __attribute__((ext_vector_type(8))) short bf16x8;
typedef __attribute__((ext_vector_type(4))) float f32x4;

static __device__ __forceinline__ float bf2f(unsigned short u) {
    return __uint_as_float(((unsigned)u) << 16);
}
static __device__ __forceinline__ unsigned short f2bf(float f) {
    unsigned u = __float_as_uint(f);
    return (unsigned short)((u + 0x7FFFu + ((u >> 16) & 1u)) >> 16);  // RNE
}
static __device__ __forceinline__ float gelu_tanh(float v) {
    const float c = 0.7978845608028654f;
    float u = c * (v + 0.044715f * v * v * v);
    return 0.5f * v * (1.0f + tanhf(u));
}
static __device__ __forceinline__ void gload16(const void* g, void* l) {
    __builtin_amdgcn_global_load_lds(
        (const __attribute__((address_space(1))) void*)g,
        (__attribute__((address_space(3))) void*)l, 16, 0, 0);
}

// ---------------- fused LayerNorm -> bf16 (one block per 768-elem row) -----
__global__ __launch_bounds__(256) void ln_bf16(
    const float* __restrict__ x, const float* __restrict__ g,
    const float* __restrict__ bta, unsigned short* __restrict__ o) {
    const size_t row = blockIdx.x;
    const float* xr = x + row * DIMD;
    unsigned short* orow = o + row * DIMD;
    const int t = threadIdx.x;
    const float v0 = xr[t], v1 = xr[t + 256], v2 = xr[t + 512];
    float s  = v0 + v1 + v2;
    float sq = v0 * v0 + v1 * v1 + v2 * v2;
    const int lane = t & 63, w = t >> 6;
    #pragma unroll
    for (int off = 32; off > 0; off >>= 1) {
        s  += __shfl_down(s, off, 64);
        sq += __shfl_down(sq, off, 64);
    }
    __shared__ float red[2][4];
    if (lane == 0) { red[0][w] = s; red[1][w] = sq; }
    __syncthreads();
    s  = red[0][0] + red[0][1] + red[0][2] + red[0][3];
    sq = red[1][0] + red[1][1] + red[1][2] + red[1][3];
    const float mu  = s * (1.0f / DIMD);
    const float var = sq * (1.0f / DIMD) - mu * mu;
    const float r = rsqrtf(var + 1e-5f);
    orow[t]       = f2bf((v0 - mu) * r * g[t]       + bta[t]);
    orow[t + 256] = f2bf((v1 - mu) * r * g[t + 256] + bta[t + 256]);
    orow[t + 512] = f2bf((v2 - mu) * r * g[t + 512] + bta[t + 512]);
}

// ---------------- weight convert + transpose: W[K,N] f32 -> Wt[N,K] bf16 ---
__global__ __launch_bounds__(256) void wconv(
    const float* __restrict__ W, unsigned short* __restrict__ Wt, int K, int N) {
    __shared__ float tile[32][33];
    const int n0 = blockIdx.x << 5, k0 = blockIdx.y << 5;
    const int tn = threadIdx.x & 31, tg = threadIdx.x >> 5;   // tg 0..7
    #pragma unroll
    for (int i = 0; i < 4; ++i) {
        const int k = (tg << 2) + i;
        tile[k][tn] = W[(size_t)(k0 + k) * N + n0 + tn];
    }
    __syncthreads();
    #pragma unroll
    for (int i = 0; i < 4; ++i) {
        const int n = (tg << 2) + i;
        Wt[(size_t)(n0 + n) * K + k0 + tn] = f2bf(tile[tn][n]);
    }
}

// ---------------- worf prep: worf_ts[h][m][c] = bf16(SCALE * worf[h][c][m])
__global__ __launch_bounds__(256) void wprep(
    const float* __restrict__ worf, unsigned short* __restrict__ worf_ts) {
    __shared__ float tile[32][33];
    const int m0 = blockIdx.x << 5, c0 = blockIdx.y << 5, h = blockIdx.z;
    const int tn = threadIdx.x & 31, tg = threadIdx.x >> 5;
    #pragma unroll
    for (int i = 0; i < 4; ++i) {
        const int c = (tg << 2) + i;
        tile[c][tn] = worf[(size_t)(h * HDIM + c0 + c) * MFEAT + m0 + tn];
    }
    __syncthreads();
    #pragma unroll
    for (int i = 0; i < 4; ++i) {
        const int m = (tg << 2) + i;
        worf_ts[(size_t)(h * MFEAT + m0 + m) * HDIM + c0 + tn] =
            f2bf(SCALE * tile[tn][m]);
    }
}

// ---------------- bf16 MFMA GEMM: C = A[M,K] @ Wt[N,K]^T + bias ------------
template <int ACT, bool RES, bool OBF16>
__global__ __launch_bounds__(256, 2) void gemm_mfma(
    const unsigned short* __restrict__ A, const unsigned short* __restrict__ Wt,
    const float* __restrict__ bias, const float* __restrict__ resid,
    void* __restrict__ Craw, int K, int N) {
    __shared__ unsigned short As[2][128 * 32];
    __shared__ unsigned short Bs[2][128 * 32];
    const int t = threadIdx.x;
    const int w = t >> 6, l = t & 63;
    const int row0 = blockIdx.y << 7, col0 = blockIdx.x << 7;
    const int wr = (w >> 1) << 6, wc = (w & 1) << 6;

    const unsigned short* ag0 = A  + (size_t)(row0 + w * 32 + (l >> 2)) * K + ((l & 3) << 3);
    const unsigned short* ag1 = ag0 + (size_t)16 * K;
    const unsigned short* bg0 = Wt + (size_t)(col0 + w * 32 + (l >> 2)) * K + ((l & 3) << 3);
    const unsigned short* bg1 = bg0 + (size_t)16 * K;

    f32x4 acc[4][4] = {};
    const int NT = K >> 5;

    auto stage = [&](int bi, int s) {
        const size_t ko = (size_t)s << 5;
        gload16(ag0 + ko, &As[bi][w * 1024]);
        gload16(ag1 + ko, &As[bi][w * 1024 + 512]);
        gload16(bg0 + ko, &Bs[bi][w * 1024]);
        gload16(bg1 + ko, &Bs[bi][w * 1024 + 512]);
    };

    stage(0, 0);
    const int lr = l & 15, lk = (l >> 4) << 3, lg = l >> 4;
    for (int s = 0; s < NT; ++s) {
        __syncthreads();
        if (s + 1 < NT) stage((s + 1) & 1, s + 1);
        const unsigned short* ab = &As[s & 1][0];
        const unsigned short* bb = &Bs[s & 1][0];
        bf16x8 af[4], bfr[4];
        #pragma unroll
        for (int f = 0; f < 4; ++f) {
            af[f]  = *(const bf16x8*)(ab + (wr + f * 16 + lr) * 32 + lk);
            bfr[f] = *(const bf16x8*)(bb + (wc + f * 16 + lr) * 32 + lk);
        }
        #pragma unroll
        for (int fi = 0; fi < 4; ++fi)
            #pragma unroll
            for (int fj = 0; fj < 4; ++fj)
                acc[fi][fj] = __builtin_amdgcn_mfma_f32_16x16x32_bf16(
                    af[fi], bfr[fj], acc[fi][fj], 0, 0, 0);
    }

    float bv[4];
    #pragma unroll
    for (int fj = 0; fj < 4; ++fj) bv[fj] = bias[col0 + wc + fj * 16 + lr];
    #pragma unroll
    for (int fi = 0; fi < 4; ++fi) {
        #pragma unroll
        for (int r = 0; r < 4; ++r) {
            const int row = row0 + wr + fi * 16 + lg * 4 + r;
            const size_t base = (size_t)row * N + col0 + wc + lr;
            #pragma unroll
            for (int fj = 0; fj < 4; ++fj) {
                float v = acc[fi][fj][r] + bv[fj];
                if constexpr (RES) v += resid[base + fj * 16];
                if constexpr (ACT == 1) v = gelu_tanh(v);
                if constexpr (OBF16) ((unsigned short*)Craw)[base + fj * 16] = f2bf(v);
                else                 ((float*)Craw)[base + fj * 16] = v;
            }
        }
    }
}

// ---------------- Phase A (MFMA): per (b,h): ktvT[c][m] (+ksum row 64) -----
// 4 waves; wave w owns m-range [w*96, w*96+96). Per 32-token tile:
//  phi:  P[n,m] = mfma(K rows n, Worf rows m) -> exp -> P_lds[m][n] (b64 pack)
//  ktv:  ktvT[c,m] += mfma(VT rows c, P rows m)  (k = n)
// VT row 64 = ones -> ktvT row 64 = ksum; rows 65..79 zero.
__global__ __launch_bounds__(256, 1) void ktv_mfma(
    const unsigned short* __restrict__ qkvb,
    const unsigned short* __restrict__ worf_ts,
    unsigned short* __restrict__ ktvT) {
    const int h = blockIdx.x, b = blockIdx.y, bh = b * HEADS + h;
    __shared__ __align__(16) unsigned short Klds[32][72];
    __shared__ __align__(16) unsigned short VT[80][40];
    __shared__ __align__(16) unsigned short P[4][96][40];
    const int t = threadIdx.x, w = t >> 6, l = t & 63;
    const int lr = l & 15, lg = l >> 4;
    const int m0 = w * 96;

    // preload loop-invariant Worf fragments (bf operand, rows m)
    bf16x8 bfw[6][2];
    #pragma unroll
    for (int mt = 0; mt < 6; ++mt)
        #pragma unroll
        for (int ks = 0; ks < 2; ++ks)
            bfw[mt][ks] = *(const bf16x8*)(worf_ts +
                (size_t)(h * MFEAT + m0 + mt * 16 + lr) * HDIM + ks * 32 + lg * 8);

    f32x4 acc[5][6] = {};   // [c-tile][m-tile]

    // VT constant rows: 64 = ones, 65..79 = zero
    for (int i = t; i < 16 * 40; i += 256) {
        const int r = 64 + i / 40, c = i % 40;
        VT[r][c] = (r == 64) ? (unsigned short)0x3F80 : (unsigned short)0;
    }
    const unsigned short* kglob = qkvb + (size_t)b * SEQ * 2304 + 768 + h * 64;
    const unsigned short* vglob = kglob + 768;

    for (int n0 = 0; n0 < SEQ; n0 += 32) {
        __syncthreads();   // previous tile's reads done
        {   // stage K tile [32][64]
            const int row = t >> 3, c8 = (t & 7) << 3;
            *(bf16x8*)&Klds[row][c8] =
                *(const bf16x8*)(kglob + (size_t)(n0 + row) * 2304 + c8);
        }
        {   // stage V^T tile [c][n]
            const int n = t & 31, c0 = (t >> 5) << 3;
            const unsigned short* src = vglob + (size_t)(n0 + n) * 2304 + c0;
            ushort4 v0 = *(const ushort4*)src;
            ushort4 v1 = *(const ushort4*)(src + 4);
            VT[c0 + 0][n] = v0.x; VT[c0 + 1][n] = v0.y;
            VT[c0 + 2][n] = v0.z; VT[c0 + 3][n] = v0.w;
            VT[c0 + 4][n] = v1.x; VT[c0 + 5][n] = v1.y;
            VT[c0 + 6][n] = v1.z; VT[c0 + 7][n] = v1.w;
        }
        __syncthreads();

        // K fragments + per-row sq
        bf16x8 afk[2][2];
        float sqv[2][4];
        #pragma unroll
        for (int ns = 0; ns < 2; ++ns) {
            float s = 0.f;
            #pragma unroll
            for (int ks = 0; ks < 2; ++ks) {
                afk[ns][ks] = *(const bf16x8*)&Klds[ns * 16 + lr][ks * 32 + lg * 8];
                #pragma unroll
                for (int j = 0; j < 8; ++j) {
                    const float f = bf2f((unsigned short)afk[ns][ks][j]);
                    s += f * f;
                }
            }
            s += __shfl_xor(s, 16);
            s += __shfl_xor(s, 32);
            s *= HALF_SCALE2;     // lane holds sq[n = ns*16 + (l&15)]
            #pragma unroll
            for (int r = 0; r < 4; ++r)
                sqv[ns][r] = __shfl(s, (lg << 2) + r);   // sq[ns*16 + lg*4 + r]
        }

        // phi -> P (wave-private)
        #pragma unroll
        for (int mt = 0; mt < 6; ++mt) {
            #pragma unroll
            for (int ns = 0; ns < 2; ++ns) {
                f32x4 p = {};
                p = __builtin_amdgcn_mfma_f32_16x16x32_bf16(afk[ns][0], bfw[mt][0], p, 0, 0, 0);
                p = __builtin_amdgcn_mfma_f32_16x16x32_bf16(afk[ns][1], bfw[mt][1], p, 0, 0, 0);
                ushort4 pk;
                pk.x = f2bf(__expf(p[0] - sqv[ns][0]));
                pk.y = f2bf(__expf(p[1] - sqv[ns][1]));
                pk.z = f2bf(__expf(p[2] - sqv[ns][2]));
                pk.w = f2bf(__expf(p[3] - sqv[ns][3]));
                *(ushort4*)&P[w][mt * 16 + lr][ns * 16 + lg * 4] = pk;
            }
        }
        asm volatile("s_waitcnt lgkmcnt(0)" ::: "memory");
        __builtin_amdgcn_sched_barrier(0);

        // ktv accumulation (k = n, 32 wide -> one MFMA per fragment)
        bf16x8 afv[5];
        #pragma unroll
        for (int ct = 0; ct < 5; ++ct)
            afv[ct] = *(const bf16x8*)&VT[ct * 16 + lr][lg * 8];
        #pragma unroll
        for (int mt = 0; mt < 6; ++mt) {
            const bf16x8 bp = *(const bf16x8*)&P[w][mt * 16 + lr][lg * 8];
            #pragma unroll
            for (int ct = 0; ct < 5; ++ct)
                acc[ct][mt] = __builtin_amdgcn_mfma_f32_16x16x32_bf16(afv[ct], bp, acc[ct][mt], 0, 0, 0);
        }
    }

    // epilogue: ktvT[bh][c][m] bf16 (c: 0..79, row 64 = ksum, 65..79 = 0)
    unsigned short* dst = ktvT + (size_t)bh * 80 * MFEAT;
    #pragma unroll
    for (int ct = 0; ct < 5; ++ct)
        #pragma unroll
        for (int mt = 0; mt < 6; ++mt)
            #pragma unroll
            for (int r = 0; r < 4; ++r) {
                const int c = ct * 16 + lg * 4 + r;
                const int m = m0 + mt * 16 + lr;
                dst[(size_t)c * MFEAT + m] = f2bf(acc[ct][mt][r]);
            }
}

// ---------------- Phase B (MFMA): out^T[c,n] = sum_m ktvT[c,m] * phi_q[n,m]
// Per block: 128 tokens; wave w owns n-range [w*32, w*32+32).
// phi (swapped): P[m,n] = mfma(Worf rows m, Q rows n) -> exp -> P_lds[n][m].
// out: acc[c,n] += mfma(ktvT rows c, P rows n) over m-chunks of 96.
// ktvT row 64 = ksum -> out^T row 64 = D.
__global__ __launch_bounds__(256) void attn_out_mfma(
    const unsigned short* __restrict__ qkvb,
    const unsigned short* __restrict__ worf_ts,
    const unsigned short* __restrict__ ktvT,
    unsigned short* __restrict__ attn) {
    const int n0 = blockIdx.x << 7;
    const int h = blockIdx.y, b = blockIdx.z, bh = b * HEADS + h;
    __shared__ __align__(16) unsigned short KT[80][104];
    __shared__ __align__(16) unsigned short P[4][32][104];
    const int t = threadIdx.x, w = t >> 6, l = t & 63;
    const int lr = l & 15, lg = l >> 4;
    const int nw = n0 + w * 32;

    // Q fragments (bf operand, rows n) + per-row sq — direct from global
    bf16x8 bq[2][2];
    float sqn[2];
    #pragma unroll
    for (int nt = 0; nt < 2; ++nt) {
        float s = 0.f;
        #pragma unroll
        for (int ks = 0; ks < 2; ++ks) {
            bq[nt][ks] = *(const bf16x8*)(qkvb +
                (size_t)(b * SEQ + nw + nt * 16 + lr) * 2304 + h * 64 + ks * 32 + lg * 8);
            #pragma unroll
            for (int j = 0; j < 8; ++j) {
                const float f = bf2f((unsigned short)bq[nt][ks][j]);
                s += f * f;
            }
        }
        s += __shfl_xor(s, 16);
        s += __shfl_xor(s, 32);
        sqn[nt] = s * HALF_SCALE2;   // sq for n = nt*16 + (l&15): lane-fixed
    }

    f32x4 acc[5][2] = {};   // [c-tile][n-tile]
    const unsigned short* ktg = ktvT + (size_t)bh * 80 * MFEAT;

    for (int ch = 0; ch < 4; ++ch) {
        const int m0 = ch * 96;
        __syncthreads();   // previous chunk's KT reads done
        for (int i = t; i < 1920; i += 256) {   // stage ktvT chunk [80][96]
            const int row = i / 24, q = i % 24;
            *(ushort4*)&KT[row][q * 4] =
                *(const ushort4*)(ktg + (size_t)row * MFEAT + m0 + q * 4);
        }
        __syncthreads();

        // phi (swapped) -> P (wave-private)
        #pragma unroll
        for (int mt = 0; mt < 6; ++mt) {
            bf16x8 afw[2];
            #pragma unroll
            for (int ks = 0; ks < 2; ++ks)
                afw[ks] = *(const bf16x8*)(worf_ts +
                    (size_t)(h * MFEAT + m0 + mt * 16 + lr) * HDIM + ks * 32 + lg * 8);
            #pragma unroll
            for (int nt = 0; nt < 2; ++nt) {
                f32x4 p = {};
                p = __builtin_amdgcn_mfma_f32_16x16x32_bf16(afw[0], bq[nt][0], p, 0, 0, 0);
                p = __builtin_amdgcn_mfma_f32_16x16x32_bf16(afw[1], bq[nt][1], p, 0, 0, 0);
                ushort4 pk;
                pk.x = f2bf(__expf(p[0] - sqn[nt]));
                pk.y = f2bf(__expf(p[1] - sqn[nt]));
                pk.z = f2bf(__expf(p[2] - sqn[nt]));
                pk.w = f2bf(__expf(p[3] - sqn[nt]));
                *(ushort4*)&P[w][nt * 16 + lr][mt * 16 + lg * 4] = pk;
            }
        }
        asm volatile("s_waitcnt lgkmcnt(0)" ::: "memory");
        __builtin_amdgcn_sched_barrier(0);

        // out accumulation over this chunk's m (3 K-steps of 32)
        #pragma unroll
        for (int ks = 0; ks < 3; ++ks) {
            bf16x8 bp[2];
            #pragma unroll
            for (int nt = 0; nt < 2; ++nt)
                bp[nt] = *(const bf16x8*)&P[w][nt * 16 + lr][ks * 32 + lg * 8];
            #pragma unroll
            for (int ct = 0; ct < 5; ++ct) {
                const bf16x8 av = *(const bf16x8*)&KT[ct * 16 + lr][ks * 32 + lg * 8];
                #pragma unroll
                for (int nt = 0; nt < 2; ++nt)
                    acc[ct][nt] = __builtin_amdgcn_mfma_f32_16x16x32_bf16(av, bp[nt], acc[ct][nt], 0, 0, 0);
            }
        }
    }

    // D (row 64) broadcast + write out
    #pragma unroll
    for (int nt = 0; nt < 2; ++nt) {
        const float d = __shfl(acc[4][nt][0], lr);   // D for this lane's col n
        const float inv = 1.0f / (d + EPSP);
        const int token = b * SEQ + nw + nt * 16 + lr;
        #pragma unroll
        for (int ct = 0; ct < 4; ++ct)
            #pragma unroll
            for (int r = 0; r < 4; ++r) {
                const int c = ct * 16 + lg * 4 + r;
                attn[(size_t)token * DIMD + h * 64 + c] = f2bf(acc[ct][nt][r] * inv);
            }
    }
}

// ---------------------------------------------------------------------------
extern "C" void kernel_launch(void* const* d_in, const int* in_sizes, int n_in,
                              void* d_out, int out_size, void* d_ws, size_t ws_size,
                              hipStream_t stream) {
    const float* x      = (const float*)d_in[0];
    const float* ln1_g  = (const float*)d_in[1];
    const float* ln1_b  = (const float*)d_in[2];
    const float* qkv_w  = (const float*)d_in[3];
    const float* qkv_b  = (const float*)d_in[4];
    const float* w_orf  = (const float*)d_in[5];
    const float* proj_w = (const float*)d_in[6];
    const float* proj_b = (const float*)d_in[7];
    const float* ln2_g  = (const float*)d_in[8];
    const float* ln2_b  = (const float*)d_in[9];
    const float* fc1_w  = (const float*)d_in[10];
    const float* fc1_b  = (const float*)d_in[11];
    const float* fc2_w  = (const float*)d_in[12];
    const float* fc2_b  = (const float*)d_in[13];
    float* out = (float*)d_out;

    // Workspace layout (bytes), total 265,814,016 B (= round-3 proven size).
    char* wsb = (char*)d_ws;
    unsigned short* qkvb    = (unsigned short*)wsb;                  // bf16 T*2304 [0, 150994944)
    unsigned short* attn    = (unsigned short*)(wsb + 150994944);    // bf16 T*768  [.., 201326592)
    unsigned short* ktvT    = (unsigned short*)(wsb + 201326592);    // bf16 384*80*384 = 23,592,960
    unsigned short* worf_ts = (unsigned short*)(wsb + 224919552);    // bf16 12*384*64 = 589,824
    unsigned short* y2      = (unsigned short*)(wsb + 201326592);    // LN2 out (ktvT/worf_ts dead)
    unsigned short* hid     = qkvb;                                  // bf16 T*3072 aliases qkvb+attn
    unsigned short* qkv_wt  = (unsigned short*)(wsb + 251658240);    // [2304,768]  3,538,944
    unsigned short* proj_wt = (unsigned short*)(wsb + 255197184);    // [768,768]   1,179,648
    unsigned short* fc1_wt  = (unsigned short*)(wsb + 256376832);    // [3072,768]  4,718,592
    unsigned short* fc2_wt  = (unsigned short*)(wsb + 261095424);    // [768,3072]  4,718,592
    unsigned short* xln     = (unsigned short*)d_out;                // bf16 T*768 in d_out (free until step 5)

    // 0) weight prep
    wconv<<<dim3(2304 / 32, 768 / 32), 256, 0, stream>>>(qkv_w, qkv_wt, DIMD, 2304);
    wconv<<<dim3(768 / 32, 768 / 32), 256, 0, stream>>>(proj_w, proj_wt, DIMD, DIMD);
    wconv<<<dim3(3072 / 32, 768 / 32), 256, 0, stream>>>(fc1_w, fc1_wt, DIMD, HIDDEN);
    wconv<<<dim3(768 / 32, 3072 / 32), 256, 0, stream>>>(fc2_w, fc2_wt, HIDDEN, DIMD);
    wprep<<<dim3(MFEAT / 32, HDIM / 32, HEADS), 256, 0, stream>>>(w_orf, worf_ts);
    // 1) xln = LN1(x) (bf16, in d_out)
    ln_bf16<<<NTOK, 256, 0, stream>>>(x, ln1_g, ln1_b, xln);
    // 2) qkv = xln @ qkv_w + qkv_b (bf16)
    gemm_mfma<0, false, true><<<dim3(2304 / 128, NTOK / 128), 256, 0, stream>>>(
        xln, qkv_wt, qkv_b, nullptr, qkvb, DIMD, 2304);
    // 3) phase A: ktvT (incl. ksum row)
    ktv_mfma<<<dim3(HEADS, BATCH), 256, 0, stream>>>(qkvb, worf_ts, ktvT);
    // 4) phase B: attn out (bf16)
    attn_out_mfma<<<dim3(SEQ / 128, HEADS, BATCH), 256, 0, stream>>>(
        qkvb, worf_ts, ktvT, attn);
    // 5) h = x + attn @ proj_w + proj_b -> d_out (f32)
    gemm_mfma<0, true, false><<<dim3(DIMD / 128, NTOK / 128), 256, 0, stream>>>(
        attn, proj_wt, proj_b, x, out, DIMD, DIMD);
    // 6) y2 = LN2(h) (bf16)
    ln_bf16<<<NTOK, 256, 0, stream>>>(out, ln2_g, ln2_b, y2);
    // 7) hid = gelu(y2 @ fc1_w + fc1_b) (bf16)
    gemm_mfma<1, false, true><<<dim3(HIDDEN / 128, NTOK / 128), 256, 0, stream>>>(
        y2, fc1_wt, fc1_b, nullptr, hid, DIMD, HIDDEN);
    // 8) out = h + hid @ fc2_w + fc2_b (in-place residual on d_out)
    gemm_mfma<0, true, false><<<dim3(DIMD / 128, NTOK / 128), 256, 0, stream>>>(
        hid, fc2_wt, fc2_b, out, out, HIDDEN, DIMD);
}